// Round 6
// baseline (130.503 us; speedup 1.0000x reference)
//
#include <hip/hip_runtime.h>

// ---------------------------------------------------------------------------
// R19: conv1 + conv2 moved to MFMA (mfma_f32_16x16x32_f16); conv3/fc VALU.
// Rationale: R14-R18 pinned at ~59us = VALU-work / 62% VALUBusy; MfmaUtil=0.
// im2col formulation: K = taps x 16 slots (8 basis | silu | silu_lo-pair | 0s);
//  - A-fragment = lane reads ONE ds_read_b128 (basis) or ONE b32 (silu pair):
//    A[row=lane&15][k=(lane>>4)*8+j]; records already match fragment layout.
//  - B pre-packed in fragment order by k_prep (global, L2-resident):
//    B[k][col=lane&15], k-chunk (lane>>4)*8; slot8=bw_hi, slot9=bw-bw_hi
//    (hi/lo split keeps bias at ~f32 precision through f16 MFMA).
//  - C/D: col=lane&15, row=(lane>>4)*4+reg (guide-verified m89/m91).
// conv1: M=676 (43 tiles), K=144 (5 ksteps); conv2: M=121 (8 tiles), K=720
// (23 ksteps). conv3 (M=81,N=2) stays VALU (K-loop too long for tiny MN).
// LDS plan (23,680B, 6 blocks/CU), strict alias/barrier schedule:
//   [0..15680)  input: REC_B 784x16B + IN_SP 784x4B      (dead after conv1)
//   [0..16900)  H1B 845x16B + H1SP 845x4B                (alias input)
//   [16900..23660) WRES f16 5x676 (conv1 raw out; disjoint from input+H1!)
//   [16900..19460) C2BUF f32 5x128 (alias WRES, post-pool)
//   [0..10890)  H2B 605x16B + SLU2 605x2B                (alias H1)
//   [16900..17548) H3F | [17552..17888) HPK | [17888..18048) RED
//   [23664..23680) ZERO16 (permanent, zero-padding A-reads)
// ---------------------------------------------------------------------------

typedef _Float16 h2 __attribute__((ext_vector_type(2)));
typedef _Float16 f16x8 __attribute__((ext_vector_type(8)));
typedef float f32x4 __attribute__((ext_vector_type(4)));

union U4H { uint4 u; f16x8 h; };

__device__ __forceinline__ h2 u2h(unsigned int u) {
  union { unsigned int x; h2 h; } v; v.x = u; return v.h;
}
__device__ __forceinline__ unsigned short f2h_bits(float x) {
  union { _Float16 h; unsigned short u; } v; v.h = (_Float16)x; return v.u;
}
__device__ __forceinline__ float h2f(unsigned short u) {
  union { unsigned short u; _Float16 h; } v; v.u = u; return (float)v.h;
}
__device__ __forceinline__ unsigned int pack2h(float a, float b) {
  return (unsigned int)f2h_bits(a) | ((unsigned int)f2h_bits(b) << 16);
}
__device__ __forceinline__ float fdot2(h2 a, h2 b, float c) {
  return __builtin_amdgcn_fdot2(a, b, c, false);
}

__device__ __forceinline__ constexpr int off1(int t) {   // conv1 tap->rec off
  return (t / 3) * 28 + (t % 3);
}
__device__ __forceinline__ constexpr int off2v(int t) {  // conv2 tap45->rec off
  return (t / 9) * 169 + ((t % 9) / 3) * 13 + ((t % 9) % 3);
}

// Basis window (8 f16 packed in uint4) + silu, all in registers.
__device__ __forceinline__ void featurize_regs(float v, uint4& bs, float& silu) {
  silu = v / (1.0f + __expf(-v));
  bs.x = 0u; bs.y = 0u; bs.z = 0u; bs.w = 0u;
  float u = fmaf(v, 2.5f, 5.5f);
  if (u >= 0.0f && u < 11.0f) {
    float tf = floorf(u);
    float f = u - tf, f2 = f * f, f3 = f2 * f, om = 1.0f - f;
    const float c6 = 1.0f / 6.0f;
    float w0 = om * om * om * c6;
    float w1 = (3.0f * f3 - 6.0f * f2 + 4.0f) * c6;
    float w2 = (-3.0f * f3 + 3.0f * f2 + 3.0f * f + 1.0f) * c6;
    float w3 = f3 * c6;
    unsigned long long w01 =
        (unsigned long long)f2h_bits(w0) |
        ((unsigned long long)f2h_bits(w1) << 16) |
        ((unsigned long long)f2h_bits(w2) << 32) |
        ((unsigned long long)f2h_bits(w3) << 48);
    int t = (int)tf;                 // 0..10; window starts at slot t-3
    int s = 16 * t - 48;             // bit shift into 128-bit field
    unsigned long long lo, hi;
    if (s >= 0) {
      lo = (s < 64) ? (w01 << s) : 0ull;
      hi = (s == 0) ? 0ull : ((s < 64) ? (w01 >> (64 - s)) : (w01 << (s - 64)));
    } else {
      lo = w01 >> (-s);
      hi = 0ull;
    }
    bs.x = (unsigned int)lo; bs.y = (unsigned int)(lo >> 32);
    bs.z = (unsigned int)hi; bs.w = (unsigned int)(hi >> 32);
  }
}

// conv3 VALU path (R18 kconv_plain, og-contiguous weights via s_load/SGPR).
template <int NO, int CHS, int ROWW>
__device__ __forceinline__ void kconv_plain(
    const uint4* bas, const unsigned short* slu,
    const uint4* __restrict__ wS, const float* __restrict__ wB,
    int y0, int x0, float (&acc)[NO]) {
  const uint4* wp = wS;
  const float* bp = wB;
  int baC = y0 * ROWW + x0;
  #pragma unroll 1
  for (int c = 0; c < 5; ++c) {
    int ba = baC;
    #pragma unroll 1
    for (int ky = 0; ky < 3; ++ky) {
      uint4 q0 = bas[ba], q1 = bas[ba + 1], q2 = bas[ba + 2];
      float s0 = h2f(slu[ba]), s1 = h2f(slu[ba + 1]), s2 = h2f(slu[ba + 2]);
      #pragma unroll
      for (int kx = 0; kx < 3; ++kx) {
        uint4 q = (kx == 0) ? q0 : ((kx == 1) ? q1 : q2);
        float sl = (kx == 0) ? s0 : ((kx == 1) ? s1 : s2);
        h2 a0 = u2h(q.x), a1 = u2h(q.y), a2 = u2h(q.z), a3 = u2h(q.w);
        #pragma unroll
        for (int j = 0; j < NO; ++j) {
          uint4 w = wp[kx * NO + j];
          float a = acc[j];
          a = fdot2(a0, u2h(w.x), a);
          a = fdot2(a1, u2h(w.y), a);
          a = fdot2(a2, u2h(w.z), a);
          a = fdot2(a3, u2h(w.w), a);
          acc[j] = fmaf(sl, bp[kx * NO + j], a);
        }
      }
      wp += 3 * NO; bp += 3 * NO;
      ba += ROWW;
    }
    baC += CHS;
  }
}

// ---------------- prep: B-fragments (conv1/conv2) + V3G + W1p4 + W2p --------
__global__ __launch_bounds__(256) void k_prep(
    const float* __restrict__ bw1, const float* __restrict__ sw1,
    const float* __restrict__ bw2, const float* __restrict__ sw2,
    const float* __restrict__ bw3, const float* __restrict__ sw3,
    const float* __restrict__ w1, const float* __restrict__ w2,
    unsigned int* __restrict__ Bc1g, unsigned int* __restrict__ B2g,
    unsigned int* __restrict__ V3Gs, float* __restrict__ V3Gb,
    unsigned int* __restrict__ W1p4, float* __restrict__ W2p) {
  int t = blockIdx.x * 256 + threadIdx.x;
  // Bc1g: 5 ksteps x 64 lanes x 4 dwords = 1280 dwords, fragment order.
  if (t < 1280) {
    int i = t & 3, l = (t >> 2) & 63, s = t >> 8;
    int k = s * 32 + ((l >> 4) & 3) * 8 + 2 * i;
    int col = l & 15, tap = k >> 4, slot = k & 15;
    unsigned int v = 0u;
    if (col < 5 && tap < 9) {
      if (slot < 8) {
        const float* sp = sw1 + (col * 9 + tap) * 8 + slot;
        v = pack2h(sp[0], sp[1]);
      } else if (slot == 8) {
        float bv = bw1[col * 9 + tap];
        float hi = (float)(_Float16)bv;
        v = pack2h(hi, bv - hi);
      }
    }
    Bc1g[t] = v;
  }
  // B2g: 23 ksteps x 64 lanes x 4 dwords = 5888 dwords.
  if (t < 5888) {
    int i = t & 3, l = (t >> 2) & 63, s = t >> 8;
    int k = s * 32 + ((l >> 4) & 3) * 8 + 2 * i;
    int col = l & 15, tap = k >> 4, slot = k & 15;
    unsigned int v = 0u;
    if (col < 5 && tap < 45) {
      if (slot < 8) {
        const float* sp = sw2 + (col * 45 + tap) * 8 + slot;
        v = pack2h(sp[0], sp[1]);
      } else if (slot == 8) {
        float bv = bw2[col * 45 + tap];
        float hi = (float)(_Float16)bv;
        v = pack2h(hi, bv - hi);
      }
    }
    B2g[t] = v;
  }
  // L3 weights: [ou][cky][kx] uint4 (R18 layout, SGPR path)
  if (t < 360) {
    int p = t & 3, u4 = t >> 2;
    int kx = u4 % 3, cky = (u4 / 3) % 15, ou = u4 / 45;
    int in = (cky / 3) * 9 + (cky % 3) * 3 + kx;
    V3Gs[t] = pack2h(sw3[(ou * 45 + in) * 8 + 2 * p], sw3[(ou * 45 + in) * 8 + 2 * p + 1]);
  }
  if (t < 90) {
    int kx = t % 3, cky = (t / 3) % 15, ou = t / 45;
    int in = (cky / 3) * 9 + (cky % 3) * 3 + kx;
    V3Gb[t] = bw3[ou * 45 + in];
  }
  if (t < 43008) {  // W1p4[((g*512)+o)*4+j]: j-th k-pair of group g, out o
    int j = t & 3, o = (t >> 2) & 511, g = t >> 11;
    int kp = g * 4 + j;
    W1p4[t] = (o < 500 && kp < 81)
                  ? pack2h(w1[o * 162 + 2 * kp], w1[o * 162 + 2 * kp + 1])
                  : 0u;
  }
  if (t < 5120) {   // W2p[10][512] zero-padded
    int o = t >> 9, k = t & 511;
    W2p[t] = (k < 500) ? w2[o * 500 + k] : 0.0f;
  }
}

// ---------------- the fused per-image kernel (four waves per block) ---------
__global__ __launch_bounds__(256, 6) void k_fused(
    const float* __restrict__ x,
    const unsigned int* __restrict__ Bc1g, const unsigned int* __restrict__ B2g,
    const unsigned int* __restrict__ V3Gs, const float* __restrict__ V3Gb,
    const unsigned int* __restrict__ W1p4, const float* __restrict__ W2p,
    const float* __restrict__ b1, const float* __restrict__ b2,
    float* __restrict__ out) {
  __shared__ __attribute__((aligned(16))) char pool[23680];
  uint4*          RECB = (uint4*)pool;                          // 784 x 16B
  unsigned int*   INSP = (unsigned int*)(pool + 12544);         // 784 x 4B
  uint4*          H1B  = (uint4*)pool;                          // 845 x 16B
  unsigned int*   H1SP = (unsigned int*)(pool + 13520);         // 845 x 4B
  unsigned short* WRES = (unsigned short*)(pool + 16900);       // 3380 f16
  float*          C2   = (float*)(pool + 16900);                // 640 f32
  uint4*          H2B  = (uint4*)pool;                          // 605 x 16B
  unsigned short* SLU2 = (unsigned short*)(pool + 9680);        // 605 u16
  float*          H3F  = (float*)(pool + 16900);                // 162 f32
  unsigned int*   HPK  = (unsigned int*)(pool + 17552);         // 84 u32
  float*          RED  = (float*)(pool + 17888);                // 40 f32
  unsigned int*   ZERO = (unsigned int*)(pool + 23664);         // 16B zeros
  float*          BASF = (float*)pool;                          // fc1out 512

  const int b   = blockIdx.x;
  const int tid = threadIdx.x;             // 0..255, four waves
  const int lane = tid & 63;
  const int wv   = tid >> 6;
  const int col  = lane & 15;              // MFMA N-col / A-row lane id
  const int hi4  = lane >> 4;              // 0..3 (k-chunk group)
  const int haf  = hi4 & 1;                // 0: basis half, 1: silu half
  const int par  = hi4 >> 1;               // 0: even tap, 1: odd tap

  // P1: featurize input image -> REC_B (basis) + IN_SP (silu,silu pair)
  if (tid < 4) ZERO[tid] = 0u;
  #pragma unroll 1
  for (int l = tid; l < 784; l += 256) {
    uint4 bs; float sl;
    featurize_regs(x[b * 784 + l], bs, sl);
    RECB[l] = bs; INSP[l] = pack2h(sl, sl);
  }
  __syncthreads();

  // P2: conv1 via MFMA. M=676 windows (43 tiles), K=144 (5 ksteps of 32).
  // C dumped to WRES f16 (disjoint region -> no barrier needed mid-phase).
  {
    U4H B1[5];
    #pragma unroll
    for (int s = 0; s < 5; ++s)
      B1[s].u = ((const uint4*)Bc1g)[s * 64 + lane];
    int mt0 = wv * 11;
    int mtn = (wv < 3) ? 11 : 10;
    #pragma unroll 1
    for (int m = 0; m < mtn; ++m) {
      int mt = mt0 + m;
      int w = mt * 16 + col;
      int wc = (w < 676) ? w : 675;        // clamp addr; write guarded
      int wy = wc / 26;
      int wbase = wy * 28 + (wc - wy * 26);
      f32x4 acc = {0.f, 0.f, 0.f, 0.f};
      #pragma unroll
      for (int s = 0; s < 5; ++s) {
        const int toV = 2 * s + 1;
        int roff = par ? ((toV < 9) ? off1(toV) : 0) : off1(2 * s);
        bool valid = (!par) || (toV < 9);  // only s=4 odd-tap invalid
        U4H a;
        if (haf == 0) {
          const uint4* ap = valid ? (RECB + (wbase + roff)) : (const uint4*)ZERO;
          a.u = *ap;
        } else {
          const unsigned int* sp = valid ? (INSP + (wbase + roff)) : ZERO;
          a.u.x = *sp; a.u.y = 0u; a.u.z = 0u; a.u.w = 0u;
        }
        acc = __builtin_amdgcn_mfma_f32_16x16x32_f16(a.h, B1[s].h, acc, 0, 0, 0);
      }
      if (col < 5) {
        #pragma unroll
        for (int r = 0; r < 4; ++r) {
          int wr = mt * 16 + hi4 * 4 + r;
          if (wr < 676) WRES[col * 676 + wr] = f2h_bits(acc[r]);
        }
      }
    }
  }
  __syncthreads();  // conv1 A-reads + WRES writes complete

  // P3: 2x2 maxpool + featurize -> H1B/H1SP (aliases input; disjoint of WRES)
  if (tid < 169) {
    int py = tid / 13, px = tid - (tid / 13) * 13;
    int w00 = py * 52 + px * 2;            // (2py)*26 + 2px (even)
    const unsigned int* W32 = (const unsigned int*)WRES;
    #pragma unroll
    for (int o = 0; o < 5; ++o) {
      unsigned int a = W32[(o * 676 + w00) >> 1];
      unsigned int c = W32[(o * 676 + w00 + 26) >> 1];
      float v = fmaxf(fmaxf(h2f((unsigned short)a), h2f((unsigned short)(a >> 16))),
                      fmaxf(h2f((unsigned short)c), h2f((unsigned short)(c >> 16))));
      uint4 bs; float sl;
      featurize_regs(v, bs, sl);
      H1B[o * 169 + tid] = bs;
      H1SP[o * 169 + tid] = pack2h(sl, sl);
    }
  }
  __syncthreads();

  // P4: conv2 via MFMA. M=121 (8 tiles, 2/wave), K=720 (23 ksteps).
  {
    int p0 = (wv * 2) * 16 + col;
    int p1 = (wv * 2 + 1) * 16 + col;
    int pc0 = (p0 < 121) ? p0 : 120;
    int pc1 = (p1 < 121) ? p1 : 120;
    int y0 = pc0 / 11, pb0 = y0 * 13 + (pc0 - y0 * 11);
    int y1 = pc1 / 11, pb1 = y1 * 13 + (pc1 - y1 * 11);
    f32x4 ac0 = {0.f, 0.f, 0.f, 0.f}, ac1 = {0.f, 0.f, 0.f, 0.f};
    #pragma unroll
    for (int s = 0; s < 23; ++s) {
      const int toV = 2 * s + 1;
      int roff = par ? ((toV < 45) ? off2v(toV) : 0) : off2v(2 * s);
      bool valid = (!par) || (toV < 45);   // only s=22 odd-tap invalid
      U4H bf; bf.u = ((const uint4*)B2g)[s * 64 + lane];
      U4H a0, a1;
      if (haf == 0) {
        const uint4* q0 = valid ? (H1B + (pb0 + roff)) : (const uint4*)ZERO;
        const uint4* q1 = valid ? (H1B + (pb1 + roff)) : (const uint4*)ZERO;
        a0.u = *q0; a1.u = *q1;
      } else {
        const unsigned int* s0p = valid ? (H1SP + (pb0 + roff)) : ZERO;
        const unsigned int* s1p = valid ? (H1SP + (pb1 + roff)) : ZERO;
        a0.u.x = *s0p; a0.u.y = 0u; a0.u.z = 0u; a0.u.w = 0u;
        a1.u.x = *s1p; a1.u.y = 0u; a1.u.z = 0u; a1.u.w = 0u;
      }
      ac0 = __builtin_amdgcn_mfma_f32_16x16x32_f16(a0.h, bf.h, ac0, 0, 0, 0);
      ac1 = __builtin_amdgcn_mfma_f32_16x16x32_f16(a1.h, bf.h, ac1, 0, 0, 0);
    }
    if (col < 5) {
      #pragma unroll
      for (int r = 0; r < 4; ++r) {
        C2[col * 128 + (wv * 2) * 16 + hi4 * 4 + r]     = ac0[r];
        C2[col * 128 + (wv * 2 + 1) * 16 + hi4 * 4 + r] = ac1[r];
      }
    }
  }
  __syncthreads();  // conv2 A-reads + C2 dump complete

  // P5: featurize h2 (rebalanced over all lanes) -> H2B/SLU2 (alias H1)
  #pragma unroll 1
  for (int k2 = 0; k2 < 3; ++k2) {
    int it = tid + 256 * k2;
    if (it < 605) {
      int o = it / 121, p = it - o * 121;
      uint4 bs; float sl;
      featurize_regs(C2[o * 128 + p], bs, sl);
      H2B[o * 121 + p] = bs;
      SLU2[o * 121 + p] = f2h_bits(sl);
    }
  }
  __syncthreads();

  // P6: conv3 (5->2) VALU; waves 0,1: out 0, waves 2,3: out 1 (R18 path)
  int og = __builtin_amdgcn_readfirstlane(tid >> 7);
  int p2 = tid & 127;
  float acc3[1] = {0.0f};
  {
    int pc = (p2 < 81) ? p2 : 80;
    int y0 = pc / 9, x0 = pc - (pc / 9) * 9;
    kconv_plain<1, 121, 11>(H2B, SLU2, (const uint4*)V3Gs + og * 45,
                            V3Gb + og * 45, y0, x0, acc3);
  }
  if (p2 < 81) H3F[og * 81 + p2] = acc3[0];   // disjoint from H2B/SLU2
  __syncthreads();
  if (tid < 84)
    HPK[tid] = (tid < 81) ? pack2h(H3F[2 * tid], H3F[2 * tid + 1]) : 0u;
  __syncthreads();

  // P7: fc1 (162->500) + bias + ReLU; 2 outs/lane; double-buffered global
  float fa[2] = {0.0f, 0.0f};
  {
    const uint4* hp4 = (const uint4*)HPK;
    const uint4* wbase = (const uint4*)W1p4 + tid;
    uint4 wA[2], wB[2];
    #pragma unroll
    for (int i = 0; i < 2; ++i) wA[i] = wbase[i * 256];   // group 0
    #pragma unroll 1
    for (int g = 0; g < 21; g += 2) {
      if (g + 1 < 21) {
        const uint4* p = wbase + (g + 1) * 512;
        #pragma unroll
        for (int i = 0; i < 2; ++i) wB[i] = p[i * 256];
      }
      {
        uint4 hk = hp4[g];
        #pragma unroll
        for (int i = 0; i < 2; ++i) {
          float a = fa[i];
          a = fdot2(u2h(hk.x), u2h(wA[i].x), a);
          a = fdot2(u2h(hk.y), u2h(wA[i].y), a);
          a = fdot2(u2h(hk.z), u2h(wA[i].z), a);
          a = fdot2(u2h(hk.w), u2h(wA[i].w), a);
          fa[i] = a;
        }
      }
      if (g + 2 < 21) {
        const uint4* p = wbase + (g + 2) * 512;
        #pragma unroll
        for (int i = 0; i < 2; ++i) wA[i] = p[i * 256];
      }
      if (g + 1 < 21) {
        uint4 hk = hp4[g + 1];
        #pragma unroll
        for (int i = 0; i < 2; ++i) {
          float a = fa[i];
          a = fdot2(u2h(hk.x), u2h(wB[i].x), a);
          a = fdot2(u2h(hk.y), u2h(wB[i].y), a);
          a = fdot2(u2h(hk.z), u2h(wB[i].z), a);
          a = fdot2(u2h(hk.w), u2h(wB[i].w), a);
          fa[i] = a;
        }
      }
    }
  }
  #pragma unroll
  for (int i = 0; i < 2; ++i) {
    int o = tid + 256 * i;
    float bb = (o < 500) ? b1[o] : 0.0f;
    float v = fa[i] + bb;
    BASF[o] = (v > 0.0f && o < 500) ? v : 0.0f;  // fc1out (alias H2B, dead)
  }
  __syncthreads();

  // P8: fc2 (500->10): lane covers k = 2*tid..2*tid+1, shfl + LDS reduction
  float acc10[10];
  {
    float2 ha = ((const float2*)BASF)[tid];
    #pragma unroll
    for (int o = 0; o < 10; ++o) {
      float2 w = ((const float2*)&W2p[o * 512])[tid];
      acc10[o] = ha.x * w.x + ha.y * w.y;
    }
  }
  #pragma unroll
  for (int off = 32; off > 0; off >>= 1) {
    #pragma unroll
    for (int o = 0; o < 10; ++o) acc10[o] += __shfl_down(acc10[o], off);
  }
  if ((tid & 63) == 0) {
    int wid = tid >> 6;
    #pragma unroll
    for (int o = 0; o < 10; ++o) RED[wid * 10 + o] = acc10[o];
  }
  __syncthreads();
  if (tid < 10)
    out[b * 10 + tid] = RED[tid] + RED[10 + tid] + RED[20 + tid] + RED[30 + tid] + b2[tid];
}

// ---------------------------------------------------------------------------
extern "C" void kernel_launch(void* const* d_in, const int* in_sizes, int n_in,
                              void* d_out, int out_size, void* d_ws, size_t ws_size,
                              hipStream_t stream) {
  (void)in_sizes; (void)n_in; (void)out_size; (void)ws_size;
  const float* x   = (const float*)d_in[0];
  const float* bw1 = (const float*)d_in[1];
  const float* sw1 = (const float*)d_in[2];
  const float* bw2 = (const float*)d_in[3];
  const float* sw2 = (const float*)d_in[4];
  const float* bw3 = (const float*)d_in[5];
  const float* sw3 = (const float*)d_in[6];
  const float* w1  = (const float*)d_in[7];
  const float* b1  = (const float*)d_in[8];
  const float* w2  = (const float*)d_in[9];
  const float* b2  = (const float*)d_in[10];
  float* out = (float*)d_out;

  char* ws = (char*)d_ws;
  unsigned int* Bc1g = (unsigned int*)(ws);            // 1,280 u  (5,120 B)
  unsigned int* B2g  = (unsigned int*)(ws + 5120);     // 5,888 u  (23,552 B)
  unsigned int* V3Gs = (unsigned int*)(ws + 28672);    // 360 u    (1,440 B)
  float*        V3Gb = (float*)(ws + 30112);           // 90 f     (360 B)
  float*        W2p  = (float*)(ws + 30720);           // 5,120 f  (20,480 B)
  unsigned int* W1p4 = (unsigned int*)(ws + 51200);    // 43,008 u (172,032 B)

  k_prep<<<168, 256, 0, stream>>>(bw1, sw1, bw2, sw2, bw3, sw3, w1, w2,
                                  Bc1g, B2g, V3Gs, V3Gb, W1p4, W2p);
  k_fused<<<2048, 256, 0, stream>>>(x, Bc1g, B2g, V3Gs, V3Gb,
                                    W1p4, W2p, b1, b2, out);
}